// Round 1
// baseline (1155.893 us; speedup 1.0000x reference)
//
#include <hip/hip_runtime.h>
#include <hip/hip_bf16.h>
#include <hip/hip_fp16.h>

// MoE: B=2,N=2048,C=1024,F=4096,E=8,K=2  (T = B*N = 4096 tokens)
// Sparse grouped-GEMM formulation: router -> per-expert token lists ->
// gather GEMM1 (relu, fp16 h) -> gather GEMM2 (scale by gate, atomicAdd to out).

#define T_TOK 4096
#define C_DIM 1024
#define F_DIM 4096
#define E_NUM 8
#define K_TOP 2

#define BM 128
#define BN 128
#define BK 64

typedef float f32x4 __attribute__((ext_vector_type(4)));
typedef _Float16 half8 __attribute__((ext_vector_type(8)));

__device__ __forceinline__ int swz(int r, int ec) { return ec ^ ((r & 7) << 3); }

// ---------------- Router: logits -> softmax -> top2 -> weights; also x -> fp16
__global__ __launch_bounds__(256) void router_kernel(
    const float* __restrict__ x, const float* __restrict__ rw,
    int* __restrict__ top_idx, float* __restrict__ top_w, _Float16* __restrict__ xh)
{
  int t = blockIdx.x * 4 + (threadIdx.x >> 6);
  int lane = threadIdx.x & 63;
  const float* xr = x + (size_t)t * C_DIM;
  float acc[E_NUM];
#pragma unroll
  for (int e = 0; e < E_NUM; ++e) acc[e] = 0.f;
  for (int j = 0; j < C_DIM / 64; ++j) {
    int c = j * 64 + lane;
    float xv = xr[c];
    xh[(size_t)t * C_DIM + c] = (_Float16)xv;
#pragma unroll
    for (int e = 0; e < E_NUM; ++e) acc[e] += xv * rw[e * C_DIM + c];
  }
#pragma unroll
  for (int e = 0; e < E_NUM; ++e) {
    float v = acc[e];
#pragma unroll
    for (int off = 32; off > 0; off >>= 1) v += __shfl_xor(v, off);
    acc[e] = v;
  }
  if (lane == 0) {
    float mx = acc[0];
    for (int e = 1; e < E_NUM; ++e) mx = fmaxf(mx, acc[e]);
    float p[E_NUM]; float Z = 0.f;
    for (int e = 0; e < E_NUM; ++e) { p[e] = expf(acc[e] - mx); Z += p[e]; }
    int b0 = 0;
    for (int e = 1; e < E_NUM; ++e) if (p[e] > p[b0]) b0 = e;
    int b1i = -1; float pb = -1.f;
    for (int e = 0; e < E_NUM; ++e) if (e != b0 && p[e] > pb) { pb = p[e]; b1i = e; }
    float p0 = p[b0] / Z, p1 = pb / Z;
    float s = p0 + p1 + 1e-9f;
    top_idx[t * 2 + 0] = b0;
    top_idx[t * 2 + 1] = b1i;
    top_w[t * 2 + 0] = p0 / s;
    top_w[t * 2 + 1] = p1 / s;
  }
}

// ---------------- Per-expert token lists (token order = deterministic)
__global__ void build_lists(const int* __restrict__ top_idx,
                            int* __restrict__ rows, int* __restrict__ counts)
{
  int e = blockIdx.x;
  int lane = threadIdx.x;  // 64 threads (one wave)
  int base = 0;
  for (int t0 = 0; t0 < T_TOK; t0 += 64) {
    int t = t0 + lane;
    int i0 = top_idx[t * 2], i1 = top_idx[t * 2 + 1];
    bool sel = (i0 == e) || (i1 == e);
    int slot = (i0 == e) ? 0 : 1;
    unsigned long long mask = __ballot(sel);
    if (sel) {
      int pos = base + __popcll(mask & ((1ull << lane) - 1ull));
      rows[e * T_TOK + pos] = t * 2 + slot;   // store t*2+slot
    }
    base += __popcll(mask);
  }
  if (lane == 0) counts[e] = base;
}

// ---------------- GEMM1: h[slot, f] = relu(x[t] . w1[e][f] + b1[e][f]), fp16 out
__global__ __launch_bounds__(256) void gemm1_kernel(
    const _Float16* __restrict__ xh, const float* __restrict__ w1,
    const float* __restrict__ b1, const int* __restrict__ rows,
    const int* __restrict__ counts, _Float16* __restrict__ hbuf,
    int fc0, int fcN)
{
  const int e = blockIdx.z;
  const int ne = counts[e];
  const int rt = blockIdx.x;
  if (rt * BM >= ne) return;
  const int ft = blockIdx.y;
  const int* rlist = rows + e * T_TOK + rt * BM;
  const float* wB = w1 + (size_t)e * F_DIM * C_DIM + (size_t)(fc0 + ft * BN) * C_DIM;

  __shared__ __align__(16) _Float16 As[BM * BK];
  __shared__ __align__(16) _Float16 Bs[BN * BK];

  const int tid = threadIdx.x;
  const int lane = tid & 63;
  const int wave = tid >> 6;
  const int wr = wave >> 1, wc = wave & 1;

  f32x4 acc[4][4];
#pragma unroll
  for (int m = 0; m < 4; ++m)
#pragma unroll
    for (int n = 0; n < 4; ++n) acc[m][n] = (f32x4){0.f, 0.f, 0.f, 0.f};

  const _Float16* asrc[4];
#pragma unroll
  for (int it = 0; it < 4; ++it) {
    int r = (tid >> 3) + 32 * it;
    int i = rt * BM + r;
    if (i < ne) {
      int slot = rlist[r];
      asrc[it] = xh + (size_t)(slot >> 1) * C_DIM + (tid & 7) * 8;
    } else asrc[it] = nullptr;
  }

  for (int k0 = 0; k0 < C_DIM; k0 += BK) {
#pragma unroll
    for (int it = 0; it < 4; ++it) {
      int r = (tid >> 3) + 32 * it;
      int cc = (tid & 7) * 8;
      int4 v = {0, 0, 0, 0};
      if (asrc[it]) v = *reinterpret_cast<const int4*>(asrc[it] + k0);
      *reinterpret_cast<int4*>(&As[r * BK + swz(r, cc)]) = v;
    }
#pragma unroll
    for (int it = 0; it < 4; ++it) {
      int r = (tid >> 3) + 32 * it;
      int cc = (tid & 7) * 8;
      const float* s = wB + (size_t)r * C_DIM + k0 + cc;
      float4 f0 = *reinterpret_cast<const float4*>(s);
      float4 f1 = *reinterpret_cast<const float4*>(s + 4);
      half8 hv;
      hv[0] = (_Float16)f0.x; hv[1] = (_Float16)f0.y; hv[2] = (_Float16)f0.z; hv[3] = (_Float16)f0.w;
      hv[4] = (_Float16)f1.x; hv[5] = (_Float16)f1.y; hv[6] = (_Float16)f1.z; hv[7] = (_Float16)f1.w;
      *reinterpret_cast<half8*>(&Bs[r * BK + swz(r, cc)]) = hv;
    }
    __syncthreads();
#pragma unroll
    for (int kk = 0; kk < BK; kk += 32) {
      const int klo = kk + (lane >> 4) * 8;
      half8 aF[4], bF[4];
#pragma unroll
      for (int m = 0; m < 4; ++m) {
        int r = wr * 64 + m * 16 + (lane & 15);
        aF[m] = *reinterpret_cast<const half8*>(&As[r * BK + swz(r, klo)]);
      }
#pragma unroll
      for (int n = 0; n < 4; ++n) {
        int r = wc * 64 + n * 16 + (lane & 15);
        bF[n] = *reinterpret_cast<const half8*>(&Bs[r * BK + swz(r, klo)]);
      }
#pragma unroll
      for (int m = 0; m < 4; ++m)
#pragma unroll
        for (int n = 0; n < 4; ++n)
          acc[m][n] = __builtin_amdgcn_mfma_f32_16x16x32_f16(aF[m], bF[n], acc[m][n], 0, 0, 0);
    }
    __syncthreads();
  }

#pragma unroll
  for (int m = 0; m < 4; ++m) {
#pragma unroll
    for (int j = 0; j < 4; ++j) {
      int iloc = wr * 64 + m * 16 + (lane >> 4) * 4 + j;
      int i = rt * BM + iloc;
      if (i < ne) {
        int slot = rlist[iloc];
#pragma unroll
        for (int n = 0; n < 4; ++n) {
          int fl = ft * BN + wc * 64 + n * 16 + (lane & 15);
          float v = acc[m][n][j] + b1[e * F_DIM + fc0 + fl];
          hbuf[(size_t)slot * fcN + fl] = (_Float16)fmaxf(v, 0.f);
        }
      }
    }
  }
}

// ---------------- GEMM2: out[t] += top_w[slot] * (h[slot] . w2[e][c] + b2[e][c])
__global__ __launch_bounds__(256) void gemm2_kernel(
    const _Float16* __restrict__ hbuf, const float* __restrict__ w2,
    const float* __restrict__ b2, const int* __restrict__ rows,
    const int* __restrict__ counts, const float* __restrict__ top_w,
    float* __restrict__ out, int fc0, int fcK, int add_bias)
{
  const int e = blockIdx.z;
  const int ne = counts[e];
  const int rt = blockIdx.x;
  if (rt * BM >= ne) return;
  const int ct = blockIdx.y;
  const int* rlist = rows + e * T_TOK + rt * BM;
  const float* wB = w2 + (size_t)e * C_DIM * F_DIM + (size_t)(ct * BN) * F_DIM + fc0;

  __shared__ __align__(16) _Float16 As[BM * BK];
  __shared__ __align__(16) _Float16 Bs[BN * BK];

  const int tid = threadIdx.x;
  const int lane = tid & 63;
  const int wave = tid >> 6;
  const int wr = wave >> 1, wc = wave & 1;

  f32x4 acc[4][4];
#pragma unroll
  for (int m = 0; m < 4; ++m)
#pragma unroll
    for (int n = 0; n < 4; ++n) acc[m][n] = (f32x4){0.f, 0.f, 0.f, 0.f};

  const _Float16* asrc[4];
#pragma unroll
  for (int it = 0; it < 4; ++it) {
    int r = (tid >> 3) + 32 * it;
    int i = rt * BM + r;
    if (i < ne) {
      int slot = rlist[r];
      asrc[it] = hbuf + (size_t)slot * fcK + (tid & 7) * 8;
    } else asrc[it] = nullptr;
  }

  for (int k0 = 0; k0 < fcK; k0 += BK) {
#pragma unroll
    for (int it = 0; it < 4; ++it) {
      int r = (tid >> 3) + 32 * it;
      int cc = (tid & 7) * 8;
      int4 v = {0, 0, 0, 0};
      if (asrc[it]) v = *reinterpret_cast<const int4*>(asrc[it] + k0);
      *reinterpret_cast<int4*>(&As[r * BK + swz(r, cc)]) = v;
    }
#pragma unroll
    for (int it = 0; it < 4; ++it) {
      int r = (tid >> 3) + 32 * it;
      int cc = (tid & 7) * 8;
      const float* s = wB + (size_t)r * F_DIM + k0 + cc;
      float4 f0 = *reinterpret_cast<const float4*>(s);
      float4 f1 = *reinterpret_cast<const float4*>(s + 4);
      half8 hv;
      hv[0] = (_Float16)f0.x; hv[1] = (_Float16)f0.y; hv[2] = (_Float16)f0.z; hv[3] = (_Float16)f0.w;
      hv[4] = (_Float16)f1.x; hv[5] = (_Float16)f1.y; hv[6] = (_Float16)f1.z; hv[7] = (_Float16)f1.w;
      *reinterpret_cast<half8*>(&Bs[r * BK + swz(r, cc)]) = hv;
    }
    __syncthreads();
#pragma unroll
    for (int kk = 0; kk < BK; kk += 32) {
      const int klo = kk + (lane >> 4) * 8;
      half8 aF[4], bF[4];
#pragma unroll
      for (int m = 0; m < 4; ++m) {
        int r = wr * 64 + m * 16 + (lane & 15);
        aF[m] = *reinterpret_cast<const half8*>(&As[r * BK + swz(r, klo)]);
      }
#pragma unroll
      for (int n = 0; n < 4; ++n) {
        int r = wc * 64 + n * 16 + (lane & 15);
        bF[n] = *reinterpret_cast<const half8*>(&Bs[r * BK + swz(r, klo)]);
      }
#pragma unroll
      for (int m = 0; m < 4; ++m)
#pragma unroll
        for (int n = 0; n < 4; ++n)
          acc[m][n] = __builtin_amdgcn_mfma_f32_16x16x32_f16(aF[m], bF[n], acc[m][n], 0, 0, 0);
    }
    __syncthreads();
  }

#pragma unroll
  for (int m = 0; m < 4; ++m) {
#pragma unroll
    for (int j = 0; j < 4; ++j) {
      int iloc = wr * 64 + m * 16 + (lane >> 4) * 4 + j;
      int i = rt * BM + iloc;
      if (i < ne) {
        int slot = rlist[iloc];
        int t = slot >> 1;
        float wgt = top_w[slot];
#pragma unroll
        for (int n = 0; n < 4; ++n) {
          int c = ct * BN + wc * 64 + n * 16 + (lane & 15);
          float v = acc[m][n][j];
          if (add_bias) v += b2[e * C_DIM + c];
          atomicAdd(out + (size_t)t * C_DIM + c, wgt * v);
        }
      }
    }
  }
}

extern "C" void kernel_launch(void* const* d_in, const int* in_sizes, int n_in,
                              void* d_out, int out_size, void* d_ws, size_t ws_size,
                              hipStream_t stream)
{
  const float* x  = (const float*)d_in[0];
  const float* rw = (const float*)d_in[1];
  const float* w1 = (const float*)d_in[2];
  const float* b1 = (const float*)d_in[3];
  const float* w2 = (const float*)d_in[4];
  const float* b2 = (const float*)d_in[5];
  float* out = (float*)d_out;

  char* ws = (char*)d_ws;
  size_t off = 0;
  auto carve = [&](size_t bytes) -> void* {
    void* p = ws + off;
    off += (bytes + 255) & ~(size_t)255;
    return p;
  };
  int*      top_idx = (int*)carve((size_t)T_TOK * 2 * sizeof(int));
  float*    top_w   = (float*)carve((size_t)T_TOK * 2 * sizeof(float));
  int*      counts  = (int*)carve(E_NUM * sizeof(int));
  int*      rows    = (int*)carve((size_t)E_NUM * T_TOK * sizeof(int));
  _Float16* xh      = (_Float16*)carve((size_t)T_TOK * C_DIM * sizeof(_Float16));
  size_t fixed = off;

  int nchunk = 32;
  const int cands[6] = {1, 2, 4, 8, 16, 32};
  for (int ci = 0; ci < 6; ++ci) {
    size_t hb = (size_t)T_TOK * K_TOP * (size_t)(F_DIM / cands[ci]) * sizeof(_Float16);
    if (fixed + hb <= ws_size) { nchunk = cands[ci]; break; }
  }
  int Fc = F_DIM / nchunk;
  _Float16* hbuf = (_Float16*)carve((size_t)T_TOK * K_TOP * (size_t)Fc * sizeof(_Float16));

  hipMemsetAsync(out, 0, (size_t)out_size * sizeof(float), stream);
  router_kernel<<<T_TOK / 4, 256, 0, stream>>>(x, rw, top_idx, top_w, xh);
  build_lists<<<E_NUM, 64, 0, stream>>>(top_idx, rows, counts);
  for (int ch = 0; ch < nchunk; ++ch) {
    gemm1_kernel<<<dim3(T_TOK / BM, Fc / BN, E_NUM), 256, 0, stream>>>(
        xh, w1, b1, rows, counts, hbuf, ch * Fc, Fc);
    gemm2_kernel<<<dim3(T_TOK / BM, C_DIM / BN, E_NUM), 256, 0, stream>>>(
        hbuf, w2, b2, rows, counts, top_w, out, ch * Fc, Fc, ch == 0);
  }
}